// Round 2
// baseline (6669.419 us; speedup 1.0000x reference)
//
#include <hip/hip_runtime.h>

typedef _Float16 f16;
typedef _Float16 f16x2 __attribute__((ext_vector_type(2)));
typedef _Float16 f16x4 __attribute__((ext_vector_type(4)));
typedef _Float16 f16x8 __attribute__((ext_vector_type(8)));
typedef float f32x4 __attribute__((ext_vector_type(4)));

#define AS1 __attribute__((address_space(1)))
#define AS3 __attribute__((address_space(3)))

static __device__ __forceinline__ float sigf(float x) { return 1.f / (1.f + __expf(-x)); }
static __device__ __forceinline__ float tanh_f(float x) { return 2.f / (1.f + __expf(-2.f * x)) - 1.f; }

// ---------------- fp32 -> fp16 ----------------
__global__ void f2h_kernel(const float* __restrict__ in, f16* __restrict__ out, int n4) {
  const int i = blockIdx.x * blockDim.x + threadIdx.x;
  if (i >= n4) return;
  const float4 v = ((const float4*)in)[i];
  f16x4 o;
  o[0] = (f16)v.x; o[1] = (f16)v.y; o[2] = (f16)v.z; o[3] = (f16)v.w;
  ((f16x4*)out)[i] = o;
}

__global__ void bias_kernel(const float* __restrict__ a, const float* __restrict__ b,
                            float* __restrict__ o, int n) {
  const int i = blockIdx.x * blockDim.x + threadIdx.x;
  if (i < n) o[i] = a[i] + b[i];
}

// ---------------- xg GEMM:  out[dir][row][g] = A[row,:]·Bt[dir*2048+g,:] + bias ----------------
__global__ __launch_bounds__(256) void gemm_xg(const f16* __restrict__ A,
                                               const f16* __restrict__ Bt,
                                               const float* __restrict__ bias,
                                               f16* __restrict__ outp, int K) {
  __shared__ f16 As[128 * 64];
  __shared__ f16 Bs[128 * 64];
  const int tid = threadIdx.x;
  const int w = tid >> 6, l = tid & 63;
  const int m0 = blockIdx.x << 7, n0 = blockIdx.y << 7;
  const int wm = w >> 1, wn = w & 1;
  f32x4 acc[4][4] = {};

  const int lr8 = l >> 3, lc8 = l & 7;
  const int gcol = (lc8 ^ lr8) << 3;

  for (int k0 = 0; k0 < K; k0 += 64) {
    __syncthreads();
#pragma unroll
    for (int j = 0; j < 4; ++j) {
      const int i = (w << 2) + j;
      const f16* ga = A + (size_t)(m0 + (i << 3) + lr8) * K + (k0 + gcol);
      __builtin_amdgcn_global_load_lds((const AS1 void*)ga, (AS3 void*)(As + (i << 9)), 16, 0, 0);
      const f16* gb = Bt + (size_t)(n0 + (i << 3) + lr8) * K + (k0 + gcol);
      __builtin_amdgcn_global_load_lds((const AS1 void*)gb, (AS3 void*)(Bs + (i << 9)), 16, 0, 0);
    }
    asm volatile("s_waitcnt vmcnt(0)" ::: "memory");
    __syncthreads();

#pragma unroll
    for (int kk = 0; kk < 2; ++kk) {
      const int cb = (kk << 6) + ((l >> 4) << 4);
      f16x8 af[4], bf[4];
#pragma unroll
      for (int a = 0; a < 4; ++a) {
        const int r = (wm << 6) + (a << 4) + (l & 15);
        af[a] = *(const f16x8*)((const char*)As + r * 128 + (cb ^ ((r & 7) << 4)));
      }
#pragma unroll
      for (int b = 0; b < 4; ++b) {
        const int r = (wn << 6) + (b << 4) + (l & 15);
        bf[b] = *(const f16x8*)((const char*)Bs + r * 128 + (cb ^ ((r & 7) << 4)));
      }
#pragma unroll
      for (int a = 0; a < 4; ++a)
#pragma unroll
        for (int b = 0; b < 4; ++b)
          acc[a][b] = __builtin_amdgcn_mfma_f32_16x16x32_f16(af[a], bf[b], acc[a][b], 0, 0, 0);
    }
  }

#pragma unroll
  for (int b = 0; b < 4; ++b) {
    const int col = n0 + (wn << 6) + (b << 4) + (l & 15);
    const float bv = bias[col];
    f16* ob = outp + (size_t)(col >> 11) * (16384ull * 2048) + (col & 2047);
#pragma unroll
    for (int a = 0; a < 4; ++a) {
      const int row0 = m0 + (wm << 6) + (a << 4) + ((l >> 4) << 2);
#pragma unroll
      for (int r = 0; r < 4; ++r)
        ob[(size_t)(row0 + r) * 2048] = (f16)(acc[a][b][r] + bv);
    }
  }
}

// ---------------- persistent bidirectional LSTM scan (one layer) ----------------
// grid: 64 WGs = 2 dirs x 32 unit-slices (16 units each). Wh slice resident in LDS.
// Sync: per-WG epoch flag (own 128B line), release-stored by tid0 after vmcnt drain;
// consumers poll all 32 flags in parallel (one per lane of wave 0).
__global__ __launch_bounds__(256) void lstm_scan(const f16* __restrict__ Whb,   // [2][2048][512]
                                                 const f16* __restrict__ xg,    // [2][16384][2048]
                                                 f16* __restrict__ hbuf,        // [2][2][32][512]
                                                 f16* __restrict__ h0_all,      // [16384][1024] (layer0)
                                                 float* __restrict__ outf,      // [16384][1024] (layer1)
                                                 float* __restrict__ hn,        // [4][32][512]
                                                 float* __restrict__ cn,        // [4][32][512]
                                                 unsigned* __restrict__ flags,
                                                 const int layer) {
  __shared__ f16 Wh_s[64 * 512];      // 64 KB, XOR-swizzled rows
  __shared__ f16 h_s[32 * 512];       // 32 KB, XOR-swizzled rows
  __shared__ float G_s[4 * 32 * 18];  // 9 KB gate exchange, stride 18 (conflict-free)

  const int tid = threadIdx.x;
  const int dir = blockIdx.x >> 5;
  const int s = blockIdx.x & 31;
  const int w = tid >> 6, l = tid & 63;

  // load Wh slice: local row lr=16g+u <- Whb row dir*2048 + 512g + 16s + u.
  // wave-coalesced: per iter each wave reads 1KB contiguous, writes XOR-permuted slots.
#pragma unroll
  for (int j = 0; j < 16; ++j) {
    const int chunk = (j << 8) + tid;     // 0..4095
    const int lr = chunk >> 6;            // 0..63
    const int cbyte = (chunk & 63) << 4;  // 0..1008
    const int g = lr >> 4, u = lr & 15;
    const char* src = (const char*)Whb + (((size_t)dir * 2048 + (g << 9) + (s << 4) + u) << 10) + cbyte;
    const uint4 v = *(const uint4*)src;
    *(uint4*)((char*)Wh_s + (lr << 10) + (cbyte ^ ((lr & 7) << 4))) = v;
  }

  unsigned* fgrp = flags + (((layer << 1) + dir) << 10);  // 1024 u32 per (layer,dir)
  const int bb = tid >> 3;  // batch row 0..31
  const int up = tid & 7;   // unit pair -> units 2up, 2up+1

  float c0 = 0.f, c1 = 0.f;
  __syncthreads();

#pragma unroll 1
  for (int t = 0; t < 512; ++t) {
    const int tau = dir ? (511 - t) : t;
    // prefetch xg for this step's cells (4 gates x 2 units) — overlaps the wait
    const f16* xr = xg + (((size_t)dir * 16384 + (size_t)bb * 512 + (size_t)tau) << 11) + (s << 4) + (up << 1);
    const f16x2 xv0 = *(const f16x2*)(xr);
    const f16x2 xv1 = *(const f16x2*)(xr + 512);
    const f16x2 xv2 = *(const f16x2*)(xr + 1024);
    const f16x2 xv3 = *(const f16x2*)(xr + 1536);

    float pi0 = 0.f, pi1 = 0.f, pf0 = 0.f, pf1 = 0.f, pg0 = 0.f, pg1 = 0.f, po0 = 0.f, po1 = 0.f;

    if (t > 0) {
      if (w == 0) {  // parallel poll: lane i watches flag of WG i
        const unsigned tgt = (unsigned)t;
        const unsigned* myf = fgrp + ((l & 31) << 5);
        unsigned v = tgt;
        int guard = 0;
        for (;;) {
          if (l < 32) v = __hip_atomic_load(myf, __ATOMIC_ACQUIRE, __HIP_MEMORY_SCOPE_AGENT);
          if (__all((int)(v >= tgt))) break;
          __builtin_amdgcn_s_sleep(1);
          if (++guard > (1 << 22)) break;
        }
      }
      __syncthreads();
      {  // stage h_t -> LDS: wave-coalesced 1KB source reads, conflict-free swizzled writes
        const f16* hsrc = hbuf + ((size_t)((dir << 1) + (t & 1)) << 14);
#pragma unroll
        for (int j = 0; j < 8; ++j) {
          const int chunk = (j << 8) + tid;     // 0..2047
          const int b = chunk >> 6;             // 0..31
          const int cbyte = (chunk & 63) << 4;  // 0..1008
          const unsigned long long* sp = (const unsigned long long*)((const char*)hsrc + (b << 10) + cbyte);
          const unsigned long long v0 =
              __hip_atomic_load(sp, __ATOMIC_RELAXED, __HIP_MEMORY_SCOPE_AGENT);
          const unsigned long long v1 =
              __hip_atomic_load(sp + 1, __ATOMIC_RELAXED, __HIP_MEMORY_SCOPE_AGENT);
          char* d = (char*)h_s + (b << 10) + (cbyte ^ ((b & 7) << 4));
          *(unsigned long long*)d = v0;
          *(unsigned long long*)(d + 8) = v1;
        }
      }
      __syncthreads();

      // G[b, 16w+u] = sum_k h[b,k] * WhS[16w+u, k]   (wave w owns gate w)
      f32x4 acc0 = {}, acc1 = {};
#pragma unroll
      for (int kk = 0; kk < 16; ++kk) {
        const int cb = (kk << 6) + ((l >> 4) << 4);
        const int ra0 = l & 15;
        const int ra1 = 16 + ra0;
        const int rb = (w << 4) + ra0;
        const f16x8 a0 = *(const f16x8*)((const char*)h_s + (ra0 << 10) + (cb ^ ((ra0 & 7) << 4)));
        const f16x8 a1 = *(const f16x8*)((const char*)h_s + (ra1 << 10) + (cb ^ ((ra1 & 7) << 4)));
        const f16x8 bv = *(const f16x8*)((const char*)Wh_s + (rb << 10) + (cb ^ ((rb & 7) << 4)));
        acc0 = __builtin_amdgcn_mfma_f32_16x16x32_f16(a0, bv, acc0, 0, 0, 0);
        acc1 = __builtin_amdgcn_mfma_f32_16x16x32_f16(a1, bv, acc1, 0, 0, 0);
      }
#pragma unroll
      for (int r = 0; r < 4; ++r) {
        const int dr = ((l >> 4) << 2) + r;
        G_s[((w << 5) + dr) * 18 + (l & 15)] = acc0[r];
        G_s[((w << 5) + 16 + dr) * 18 + (l & 15)] = acc1[r];
      }
      __syncthreads();

      const float* gp = G_s + bb * 18 + (up << 1);
      const float2 vi = *(const float2*)(gp);
      const float2 vf = *(const float2*)(gp + 576);
      const float2 vg = *(const float2*)(gp + 1152);
      const float2 vo = *(const float2*)(gp + 1728);
      pi0 = vi.x; pi1 = vi.y; pf0 = vf.x; pf1 = vf.y;
      pg0 = vg.x; pg1 = vg.y; po0 = vo.x; po1 = vo.y;
    }

    pi0 += (float)xv0[0]; pi1 += (float)xv0[1];
    pf0 += (float)xv1[0]; pf1 += (float)xv1[1];
    pg0 += (float)xv2[0]; pg1 += (float)xv2[1];
    po0 += (float)xv3[0]; po1 += (float)xv3[1];

    const float i0 = sigf(pi0), i1 = sigf(pi1);
    const float f0 = sigf(pf0), f1 = sigf(pf1);
    const float g0 = tanh_f(pg0), g1 = tanh_f(pg1);
    const float o0 = sigf(po0), o1 = sigf(po1);
    c0 = f0 * c0 + i0 * g0;
    c1 = f1 * c1 + i1 * g1;
    const float h0v = o0 * tanh_f(c0);
    const float h1v = o1 * tanh_f(c1);

    union { f16x2 h2; unsigned u; } pk;
    pk.h2[0] = (f16)h0v; pk.h2[1] = (f16)h1v;

    // publish h_{t+1} (agent-scope store) then release this WG's epoch flag
    {
      const size_t e = ((size_t)((dir << 1) + ((t + 1) & 1)) << 14) + ((size_t)bb << 9) + (s << 4) + (up << 1);
      __hip_atomic_store((unsigned*)(hbuf + e), pk.u, __ATOMIC_RELAXED, __HIP_MEMORY_SCOPE_AGENT);
    }
    asm volatile("s_waitcnt vmcnt(0)" ::: "memory");  // per-thread drain of publish
    __syncthreads();                                  // all threads' publishes complete
    if (tid == 0)
      __hip_atomic_store(fgrp + (s << 5), (unsigned)(t + 1), __ATOMIC_RELEASE, __HIP_MEMORY_SCOPE_AGENT);

    // epilogue stores AFTER the flag — off the critical path
    const size_t orow = (((size_t)bb * 512 + (size_t)tau) << 10) + ((size_t)dir << 9) + (s << 4) + (up << 1);
    if (layer == 0) {
      *(unsigned*)(h0_all + orow) = pk.u;
    } else {
      *(float2*)(outf + orow) = make_float2(h0v, h1v);
    }
    if (t == 511) {
      const size_t nidx = (((size_t)(layer << 1) + (size_t)dir) << 14) + ((size_t)bb << 9) + (s << 4) + (up << 1);
      *(float2*)(hn + nidx) = make_float2(h0v, h1v);
      *(float2*)(cn + nidx) = make_float2(c0, c1);
    }
  }
}

// ---------------- host ----------------
extern "C" void kernel_launch(void* const* d_in, const int* in_sizes, int n_in,
                              void* d_out, int out_size, void* d_ws, size_t ws_size,
                              hipStream_t stream) {
  const float* x = (const float*)d_in[0];
  const float* Wx0 = (const float*)d_in[1];
  const float* Wh0 = (const float*)d_in[2];
  const float* bx0 = (const float*)d_in[3];
  const float* bh0 = (const float*)d_in[4];
  const float* Wx1 = (const float*)d_in[5];
  const float* Wh1 = (const float*)d_in[6];
  const float* bx1 = (const float*)d_in[7];
  const float* bh1 = (const float*)d_in[8];

  char* ws = (char*)d_ws;
  size_t off = 0;
  auto alloc = [&](size_t b) { char* p = ws + off; off += (b + 255) & ~(size_t)255; return p; };
  f16* xg = (f16*)alloc(2ull * 16384 * 2048 * 2);      // 134 MB (reused both layers)
  f16* x_h = (f16*)alloc(16384ull * 512 * 2);          // 16.8 MB
  f16* h0a = (f16*)alloc(16384ull * 1024 * 2);         // 33.6 MB
  f16* Wx0h = (f16*)alloc(2ull * 2048 * 512 * 2);
  f16* Wh0h = (f16*)alloc(2ull * 2048 * 512 * 2);
  f16* Wx1h = (f16*)alloc(2ull * 2048 * 1024 * 2);
  f16* Wh1h = (f16*)alloc(2ull * 2048 * 512 * 2);
  float* bias0 = (float*)alloc(4096 * 4);
  float* bias1 = (float*)alloc(4096 * 4);
  f16* hbuf = (f16*)alloc(2ull * 2 * 32 * 512 * 2);
  unsigned* flags = (unsigned*)alloc(4ull * 1024 * 4);  // [layer][dir][32 wg] on 128B lines
  if (off > ws_size) return;  // needs ~206 MB of workspace

  float* outp = (float*)d_out;
  float* hn = outp + 16384ull * 1024;
  float* cn = hn + 4ull * 32 * 512;

  hipMemsetAsync(flags, 0, 4ull * 1024 * 4, stream);

  f2h_kernel<<<dim3(2097152 / 256), 256, 0, stream>>>(x, x_h, 2097152);
  f2h_kernel<<<dim3(524288 / 256), 256, 0, stream>>>(Wx0, Wx0h, 524288);
  f2h_kernel<<<dim3(524288 / 256), 256, 0, stream>>>(Wh0, Wh0h, 524288);
  f2h_kernel<<<dim3(1048576 / 256), 256, 0, stream>>>(Wx1, Wx1h, 1048576);
  f2h_kernel<<<dim3(524288 / 256), 256, 0, stream>>>(Wh1, Wh1h, 524288);
  bias_kernel<<<16, 256, 0, stream>>>(bx0, bh0, bias0, 4096);
  bias_kernel<<<16, 256, 0, stream>>>(bx1, bh1, bias1, 4096);

  dim3 g(128, 32);
  gemm_xg<<<g, 256, 0, stream>>>(x_h, Wx0h, bias0, xg, 512);
  lstm_scan<<<64, 256, 0, stream>>>(Wh0h, xg, hbuf, h0a, nullptr, hn, cn, flags, 0);
  gemm_xg<<<g, 256, 0, stream>>>(h0a, Wx1h, bias1, xg, 1024);
  lstm_scan<<<64, 256, 0, stream>>>(Wh1h, xg, hbuf, nullptr, outp, hn, cn, flags, 1);
}

// Round 3
// 5186.971 us; speedup vs baseline: 1.2858x; 1.2858x over previous
//
#include <hip/hip_runtime.h>

typedef _Float16 f16;
typedef _Float16 f16x2 __attribute__((ext_vector_type(2)));
typedef _Float16 f16x4 __attribute__((ext_vector_type(4)));
typedef _Float16 f16x8 __attribute__((ext_vector_type(8)));
typedef float f32x4 __attribute__((ext_vector_type(4)));

#define AS1 __attribute__((address_space(1)))
#define AS3 __attribute__((address_space(3)))

static __device__ __forceinline__ float sigf(float x) { return 1.f / (1.f + __expf(-x)); }
static __device__ __forceinline__ float tanh_f(float x) { return 2.f / (1.f + __expf(-2.f * x)) - 1.f; }

// ---------------- fp32 -> fp16 ----------------
__global__ void f2h_kernel(const float* __restrict__ in, f16* __restrict__ out, int n4) {
  const int i = blockIdx.x * blockDim.x + threadIdx.x;
  if (i >= n4) return;
  const float4 v = ((const float4*)in)[i];
  f16x4 o;
  o[0] = (f16)v.x; o[1] = (f16)v.y; o[2] = (f16)v.z; o[3] = (f16)v.w;
  ((f16x4*)out)[i] = o;
}

__global__ void bias_kernel(const float* __restrict__ a, const float* __restrict__ b,
                            float* __restrict__ o, int n) {
  const int i = blockIdx.x * blockDim.x + threadIdx.x;
  if (i < n) o[i] = a[i] + b[i];
}

// ---------------- xg GEMM:  out[dir][row][g] = A[row,:]·Bt[dir*2048+g,:] + bias ----------------
__global__ __launch_bounds__(256) void gemm_xg(const f16* __restrict__ A,
                                               const f16* __restrict__ Bt,
                                               const float* __restrict__ bias,
                                               f16* __restrict__ outp, int K) {
  __shared__ f16 As[128 * 64];
  __shared__ f16 Bs[128 * 64];
  const int tid = threadIdx.x;
  const int w = tid >> 6, l = tid & 63;
  const int m0 = blockIdx.x << 7, n0 = blockIdx.y << 7;
  const int wm = w >> 1, wn = w & 1;
  f32x4 acc[4][4] = {};

  const int lr8 = l >> 3, lc8 = l & 7;
  const int gcol = (lc8 ^ lr8) << 3;

  for (int k0 = 0; k0 < K; k0 += 64) {
    __syncthreads();
#pragma unroll
    for (int j = 0; j < 4; ++j) {
      const int i = (w << 2) + j;
      const f16* ga = A + (size_t)(m0 + (i << 3) + lr8) * K + (k0 + gcol);
      __builtin_amdgcn_global_load_lds((const AS1 void*)ga, (AS3 void*)(As + (i << 9)), 16, 0, 0);
      const f16* gb = Bt + (size_t)(n0 + (i << 3) + lr8) * K + (k0 + gcol);
      __builtin_amdgcn_global_load_lds((const AS1 void*)gb, (AS3 void*)(Bs + (i << 9)), 16, 0, 0);
    }
    asm volatile("s_waitcnt vmcnt(0)" ::: "memory");
    __syncthreads();

#pragma unroll
    for (int kk = 0; kk < 2; ++kk) {
      const int cb = (kk << 6) + ((l >> 4) << 4);
      f16x8 af[4], bf[4];
#pragma unroll
      for (int a = 0; a < 4; ++a) {
        const int r = (wm << 6) + (a << 4) + (l & 15);
        af[a] = *(const f16x8*)((const char*)As + r * 128 + (cb ^ ((r & 7) << 4)));
      }
#pragma unroll
      for (int b = 0; b < 4; ++b) {
        const int r = (wn << 6) + (b << 4) + (l & 15);
        bf[b] = *(const f16x8*)((const char*)Bs + r * 128 + (cb ^ ((r & 7) << 4)));
      }
#pragma unroll
      for (int a = 0; a < 4; ++a)
#pragma unroll
        for (int b = 0; b < 4; ++b)
          acc[a][b] = __builtin_amdgcn_mfma_f32_16x16x32_f16(af[a], bf[b], acc[a][b], 0, 0, 0);
    }
  }

#pragma unroll
  for (int b = 0; b < 4; ++b) {
    const int col = n0 + (wn << 6) + (b << 4) + (l & 15);
    const float bv = bias[col];
    f16* ob = outp + (size_t)(col >> 11) * (16384ull * 2048) + (col & 2047);
#pragma unroll
    for (int a = 0; a < 4; ++a) {
      const int row0 = m0 + (wm << 6) + (a << 4) + ((l >> 4) << 2);
#pragma unroll
      for (int r = 0; r < 4; ++r)
        ob[(size_t)(row0 + r) * 2048] = (f16)(acc[a][b][r] + bv);
    }
  }
}

// ---------------- persistent bidirectional LSTM scan (one layer) ----------------
// grid: 64 WGs = 2 dirs x 32 unit-slices (16 units each). Wh slice resident in LDS.
// Sync: NO flags. Each h unit-pair is published as one 8B atomic {tag=epoch, data}
// into a 4-slot ring (slot = epoch&3). Consumers poll the payload directly; tag
// arrives atomically with its data, so readiness == validity. No fences, no drains.
// Ring WAR safety: h_{u+4} is value-dependent on every WG's staging reads of slot u.
__global__ __launch_bounds__(256) void lstm_scan(const f16* __restrict__ Whb,   // [2][2048][512]
                                                 const f16* __restrict__ xg,    // [2][16384][2048]
                                                 unsigned long long* __restrict__ ring,  // [2][4][32][256] {tag,data}
                                                 f16* __restrict__ h0_all,      // [16384][1024] (layer0)
                                                 float* __restrict__ outf,      // [16384][1024] (layer1)
                                                 float* __restrict__ hn,        // [4][32][512]
                                                 float* __restrict__ cn,        // [4][32][512]
                                                 const int layer) {
  __shared__ f16 Wh_s[64 * 512];      // 64 KB, XOR-swizzled rows
  __shared__ f16 h_s[32 * 512];       // 32 KB, XOR-swizzled rows
  __shared__ float G_s[4 * 32 * 18];  // 9 KB gate exchange, stride 18

  const int tid = threadIdx.x;
  const int dir = blockIdx.x >> 5;
  const int s = blockIdx.x & 31;
  const int w = tid >> 6, l = tid & 63;

  // load Wh slice: local row lr=16g+u <- Whb row dir*2048 + 512g + 16s + u (wave-coalesced)
#pragma unroll
  for (int j = 0; j < 16; ++j) {
    const int chunk = (j << 8) + tid;
    const int lr = chunk >> 6;
    const int cbyte = (chunk & 63) << 4;
    const int g = lr >> 4, u = lr & 15;
    const char* src = (const char*)Whb + (((size_t)dir * 2048 + (g << 9) + (s << 4) + u) << 10) + cbyte;
    const uint4 v = *(const uint4*)src;
    *(uint4*)((char*)Wh_s + (lr << 10) + (cbyte ^ ((lr & 7) << 4))) = v;
  }

  unsigned long long* rdir = ring + ((size_t)dir << 15);  // 4*32*256 = 32768 entries per dir
  const int bb = tid >> 3;  // batch row 0..31
  const int up = tid & 7;   // unit pair -> units 2up, 2up+1

  float c0 = 0.f, c1 = 0.f;
  __syncthreads();

#pragma unroll 1
  for (int t = 0; t < 512; ++t) {
    const int tau = dir ? (511 - t) : t;
    // prefetch xg for this step's cells (4 gates x 2 units) — overlaps the poll
    const f16* xr = xg + (((size_t)dir * 16384 + (size_t)bb * 512 + (size_t)tau) << 11) + (s << 4) + (up << 1);
    const f16x2 xv0 = *(const f16x2*)(xr);
    const f16x2 xv1 = *(const f16x2*)(xr + 512);
    const f16x2 xv2 = *(const f16x2*)(xr + 1024);
    const f16x2 xv3 = *(const f16x2*)(xr + 1536);

    float pi0 = 0.f, pi1 = 0.f, pf0 = 0.f, pf1 = 0.f, pg0 = 0.f, pg1 = 0.f, po0 = 0.f, po1 = 0.f;

    if (t > 0) {
      const unsigned tgt = (unsigned)t;
      const unsigned long long* rs = rdir + ((size_t)(t & 3) << 13);  // slot: 32*256 entries
      unsigned long long v[8][4];
      // optimistic burst: issue all 32 independent 8B loads first
#pragma unroll
      for (int j = 0; j < 8; ++j) {
        const int chunk = (j << 8) + tid;
        const unsigned long long* sp = rs + ((chunk >> 6) << 8) + ((chunk & 63) << 2);
#pragma unroll
        for (int q = 0; q < 4; ++q)
          v[j][q] = __hip_atomic_load(sp + q, __ATOMIC_RELAXED, __HIP_MEMORY_SCOPE_AGENT);
      }
      // per-chunk verify/retry, then stage to LDS (XOR-swizzled)
#pragma unroll
      for (int j = 0; j < 8; ++j) {
        const int chunk = (j << 8) + tid;
        const int b = chunk >> 6;
        const unsigned long long* sp = rs + (b << 8) + ((chunk & 63) << 2);
        int guard = 0;
        while (!(((unsigned)v[j][0] == tgt) & ((unsigned)v[j][1] == tgt) &
                 ((unsigned)v[j][2] == tgt) & ((unsigned)v[j][3] == tgt))) {
#pragma unroll
          for (int q = 0; q < 4; ++q)
            v[j][q] = __hip_atomic_load(sp + q, __ATOMIC_RELAXED, __HIP_MEMORY_SCOPE_AGENT);
          if (++guard > (1 << 20)) break;
        }
        uint4 d;
        d.x = (unsigned)(v[j][0] >> 32);
        d.y = (unsigned)(v[j][1] >> 32);
        d.z = (unsigned)(v[j][2] >> 32);
        d.w = (unsigned)(v[j][3] >> 32);
        const int cbyte = (chunk & 63) << 4;
        *(uint4*)((char*)h_s + (b << 10) + (cbyte ^ ((b & 7) << 4))) = d;
      }
      __syncthreads();

      // G[b, 16w+u] = sum_k h[b,k] * WhS[16w+u, k]   (wave w owns gate w)
      f32x4 acc0 = {}, acc1 = {};
#pragma unroll
      for (int kk = 0; kk < 16; ++kk) {
        const int cb = (kk << 6) + ((l >> 4) << 4);
        const int ra0 = l & 15;
        const int ra1 = 16 + ra0;
        const int rb = (w << 4) + ra0;
        const f16x8 a0 = *(const f16x8*)((const char*)h_s + (ra0 << 10) + (cb ^ ((ra0 & 7) << 4)));
        const f16x8 a1 = *(const f16x8*)((const char*)h_s + (ra1 << 10) + (cb ^ ((ra1 & 7) << 4)));
        const f16x8 bv = *(const f16x8*)((const char*)Wh_s + (rb << 10) + (cb ^ ((rb & 7) << 4)));
        acc0 = __builtin_amdgcn_mfma_f32_16x16x32_f16(a0, bv, acc0, 0, 0, 0);
        acc1 = __builtin_amdgcn_mfma_f32_16x16x32_f16(a1, bv, acc1, 0, 0, 0);
      }
#pragma unroll
      for (int r = 0; r < 4; ++r) {
        const int dr = ((l >> 4) << 2) + r;
        G_s[((w << 5) + dr) * 18 + (l & 15)] = acc0[r];
        G_s[((w << 5) + 16 + dr) * 18 + (l & 15)] = acc1[r];
      }
      __syncthreads();

      const float* gp = G_s + bb * 18 + (up << 1);
      const float2 vi = *(const float2*)(gp);
      const float2 vf = *(const float2*)(gp + 576);
      const float2 vg = *(const float2*)(gp + 1152);
      const float2 vo = *(const float2*)(gp + 1728);
      pi0 = vi.x; pi1 = vi.y; pf0 = vf.x; pf1 = vf.y;
      pg0 = vg.x; pg1 = vg.y; po0 = vo.x; po1 = vo.y;
    }

    pi0 += (float)xv0[0]; pi1 += (float)xv0[1];
    pf0 += (float)xv1[0]; pf1 += (float)xv1[1];
    pg0 += (float)xv2[0]; pg1 += (float)xv2[1];
    po0 += (float)xv3[0]; po1 += (float)xv3[1];

    const float i0 = sigf(pi0), i1 = sigf(pi1);
    const float f0 = sigf(pf0), f1 = sigf(pf1);
    const float g0 = tanh_f(pg0), g1 = tanh_f(pg1);
    const float o0 = sigf(po0), o1 = sigf(po1);
    c0 = f0 * c0 + i0 * g0;
    c1 = f1 * c1 + i1 * g1;
    const float h0v = o0 * tanh_f(c0);
    const float h1v = o1 * tanh_f(c1);

    union { f16x2 h2; unsigned u; } pk;
    pk.h2[0] = (f16)h0v; pk.h2[1] = (f16)h1v;

    // publish h_{t+1}: single 8B atomic {tag = t+1, data} — fire and forget
    {
      const size_t ridx = ((size_t)((t + 1) & 3) << 13) + ((size_t)bb << 8) + (s << 3) + up;
      const unsigned long long pv = ((unsigned long long)pk.u << 32) | (unsigned long long)(t + 1);
      __hip_atomic_store(rdir + ridx, pv, __ATOMIC_RELAXED, __HIP_MEMORY_SCOPE_AGENT);
    }

    // epilogue stores — off the critical path
    const size_t orow = (((size_t)bb * 512 + (size_t)tau) << 10) + ((size_t)dir << 9) + (s << 4) + (up << 1);
    if (layer == 0) {
      *(unsigned*)(h0_all + orow) = pk.u;
    } else {
      *(float2*)(outf + orow) = make_float2(h0v, h1v);
    }
    if (t == 511) {
      const size_t nidx = (((size_t)(layer << 1) + (size_t)dir) << 14) + ((size_t)bb << 9) + (s << 4) + (up << 1);
      *(float2*)(hn + nidx) = make_float2(h0v, h1v);
      *(float2*)(cn + nidx) = make_float2(c0, c1);
    }
  }
}

// ---------------- host ----------------
extern "C" void kernel_launch(void* const* d_in, const int* in_sizes, int n_in,
                              void* d_out, int out_size, void* d_ws, size_t ws_size,
                              hipStream_t stream) {
  const float* x = (const float*)d_in[0];
  const float* Wx0 = (const float*)d_in[1];
  const float* Wh0 = (const float*)d_in[2];
  const float* bx0 = (const float*)d_in[3];
  const float* bh0 = (const float*)d_in[4];
  const float* Wx1 = (const float*)d_in[5];
  const float* Wh1 = (const float*)d_in[6];
  const float* bx1 = (const float*)d_in[7];
  const float* bh1 = (const float*)d_in[8];

  char* ws = (char*)d_ws;
  size_t off = 0;
  auto alloc = [&](size_t b) { char* p = ws + off; off += (b + 255) & ~(size_t)255; return p; };
  f16* xg = (f16*)alloc(2ull * 16384 * 2048 * 2);      // 134 MB (reused both layers)
  f16* x_h = (f16*)alloc(16384ull * 512 * 2);          // 16.8 MB
  f16* h0a = (f16*)alloc(16384ull * 1024 * 2);         // 33.6 MB
  f16* Wx0h = (f16*)alloc(2ull * 2048 * 512 * 2);
  f16* Wh0h = (f16*)alloc(2ull * 2048 * 512 * 2);
  f16* Wx1h = (f16*)alloc(2ull * 2048 * 1024 * 2);
  f16* Wh1h = (f16*)alloc(2ull * 2048 * 512 * 2);
  float* bias0 = (float*)alloc(4096 * 4);
  float* bias1 = (float*)alloc(4096 * 4);
  unsigned long long* ring0 = (unsigned long long*)alloc(2ull * 4 * 32 * 256 * 8);  // 512 KB
  unsigned long long* ring1 = (unsigned long long*)alloc(2ull * 4 * 32 * 256 * 8);  // 512 KB
  if (off > ws_size) return;  // needs ~207 MB of workspace

  float* outp = (float*)d_out;
  float* hn = outp + 16384ull * 1024;
  float* cn = hn + 4ull * 32 * 512;

  // clear ring tags (stale tags from a previous replay would alias epochs)
  hipMemsetAsync(ring0, 0, 2ull * 4 * 32 * 256 * 8, stream);
  hipMemsetAsync(ring1, 0, 2ull * 4 * 32 * 256 * 8, stream);

  f2h_kernel<<<dim3(2097152 / 256), 256, 0, stream>>>(x, x_h, 2097152);
  f2h_kernel<<<dim3(524288 / 256), 256, 0, stream>>>(Wx0, Wx0h, 524288);
  f2h_kernel<<<dim3(524288 / 256), 256, 0, stream>>>(Wh0, Wh0h, 524288);
  f2h_kernel<<<dim3(1048576 / 256), 256, 0, stream>>>(Wx1, Wx1h, 1048576);
  f2h_kernel<<<dim3(524288 / 256), 256, 0, stream>>>(Wh1, Wh1h, 524288);
  bias_kernel<<<16, 256, 0, stream>>>(bx0, bh0, bias0, 4096);
  bias_kernel<<<16, 256, 0, stream>>>(bx1, bh1, bias1, 4096);

  dim3 g(128, 32);
  gemm_xg<<<g, 256, 0, stream>>>(x_h, Wx0h, bias0, xg, 512);
  lstm_scan<<<64, 256, 0, stream>>>(Wh0h, xg, ring0, h0a, nullptr, hn, cn, 0);
  gemm_xg<<<g, 256, 0, stream>>>(h0a, Wx1h, bias1, xg, 1024);
  lstm_scan<<<64, 256, 0, stream>>>(Wh1h, xg, ring1, nullptr, outp, hn, cn, 1);
}